// Round 8
// baseline (66.657 us; speedup 1.0000x reference)
//
#include <hip/hip_runtime.h>
#include <stdint.h>

// Problem constants (match reference)
#define BB 16384
#define SS 20
#define DD 128
#define EPSV 1e-5f

// One wave (64 lanes) per batch row; each lane owns 2 consecutive d
// (d0 = 2*lane) entirely in registers. Conv taps +-1,+-2,+-4 via ds_bpermute
// from lanes +-1,+-2 (8 per row t). No LDS tile, no barrier, no launch-bounds
// cap (R6: a VGPR cap below ~90 live regs -> catastrophic scratch spill).
// R8: t-loop FULLY unrolled so weight s_loads pipeline across iterations
// (R7: unroll 1 -> per-iteration ~200cyc s_load convoy -> VALUBusy 59%).
// Gate matvec uses v_dot2_f32_f16 on f16-packed xn and gate_w (packed once
// by a prep kernel into d_ws) -> 20 insts/t instead of 40.

typedef __fp16 half2_t __attribute__((ext_vector_type(2)));

#define BPERM(addr, v) \
    __int_as_float(__builtin_amdgcn_ds_bpermute((addr), __float_as_int(v)))

#if defined(__has_builtin)
#if __has_builtin(__builtin_amdgcn_fdot2)
#define HAVE_FDOT2 1
#endif
#endif
#ifndef HAVE_FDOT2
#define HAVE_FDOT2 0
#endif

static __device__ __forceinline__ float gate_dot2(half2_t a, half2_t b, float c) {
#if HAVE_FDOT2
    return __builtin_amdgcn_fdot2(a, b, c, false);
#else
    c = fmaf((float)a[0], (float)b[0], c);
    return fmaf((float)a[1], (float)b[1], c);
#endif
}

// ---- prep: pack gate_w [20][20] f32 -> [20][10] f16x2 in ws ----
__global__ void pack_gate_kernel(const float* __restrict__ gate_w,
                                 uint32_t*    __restrict__ ws) {
    const int i = threadIdx.x;            // single block of 256
    if (i < SS * (SS / 2)) {
        const int t = i / (SS / 2), p = i % (SS / 2);
        half2_t h;
        h[0] = (__fp16)gate_w[t * SS + 2 * p];
        h[1] = (__fp16)gate_w[t * SS + 2 * p + 1];
        ws[i] = __builtin_bit_cast(uint32_t, h);
    }
}

__global__ __launch_bounds__(256) void fused_mdt_kernel(
    const int*      __restrict__ tokens,   // [B,S]
    const float*    __restrict__ emb,      // [V,D] (6 KB, cache-resident)
    const float*    __restrict__ pre_w,    // [S]
    const float*    __restrict__ w0, const float* __restrict__ b0,
    const float*    __restrict__ w1, const float* __restrict__ b1,
    const float*    __restrict__ w2, const float* __restrict__ b2,
    const uint32_t* __restrict__ gw_pk,    // [S][S/2] f16x2 (from prep)
    const float*    __restrict__ gate_b,   // [S]
    const float*    __restrict__ post_w,   // [S]
    const float*    __restrict__ logit_w,  // [1,S,1] -> flat [S]
    float*          __restrict__ out)      // [B,1,D] -> flat [B*D]
{
    const int tid  = threadIdx.x;
    const int lane = tid & 63;               // one row per wave
    const int b    = __builtin_amdgcn_readfirstlane(blockIdx.x * 4 + (tid >> 6));
    const int d0   = lane << 1;

    // edge masks ('same' zero padding)
    const bool mL1 = (lane == 0);
    const bool mL2 = (lane <  2);
    const bool mR1 = (lane == 63);
    const bool mR2 = (lane >= 62);
    // bpermute addresses (wraps are always masked)
    const int aL1 = (lane - 1) << 2;
    const int aL2 = (lane - 2) << 2;
    const int aR1 = (lane + 1) << 2;
    const int aR2 = (lane + 2) << 2;

    // ---- emb gather (tok[] scoped: dies before the main loop) ----
    float x0[SS], x1[SS];
    {
        int tok[SS];
        const int4* t4 = reinterpret_cast<const int4*>(tokens + b * SS);
        #pragma unroll
        for (int i = 0; i < 5; ++i) {
            int4 v = t4[i];
            tok[4*i+0] = v.x; tok[4*i+1] = v.y;
            tok[4*i+2] = v.z; tok[4*i+3] = v.w;
        }
        #pragma unroll
        for (int s = 0; s < SS; ++s) {
            const float2 v = *reinterpret_cast<const float2*>(emb + tok[s] * DD + d0);
            x0[s] = v.x; x1[s] = v.y;
        }
    }

    // ---- per-d RMS stats + residual dot ----
    float ms0 = 0.f, ms1 = 0.f, a10 = 0.f, a11 = 0.f;
    #pragma unroll
    for (int s = 0; s < SS; ++s) {
        ms0 = fmaf(x0[s], x0[s], ms0);
        ms1 = fmaf(x1[s], x1[s], ms1);
        const float lw = logit_w[s];
        a10 = fmaf(x0[s], lw, a10);
        a11 = fmaf(x1[s], lw, a11);
    }
    const float r0 = rsqrtf(ms0 * (1.f/SS) + EPSV);
    const float r1 = rsqrtf(ms1 * (1.f/SS) + EPSV);

    // ---- x_norm in place + f16x2 packed copies for the gate ----
    half2_t xp0[SS/2], xp1[SS/2];
    #pragma unroll
    for (int s = 0; s < SS; ++s) {
        const float pw = pre_w[s];
        x0[s] *= r0 * pw;
        x1[s] *= r1 * pw;
    }
    #pragma unroll
    for (int p = 0; p < SS/2; ++p) {
        half2_t h0; h0[0] = (__fp16)x0[2*p]; h0[1] = (__fp16)x0[2*p+1];
        half2_t h1; h1[0] = (__fp16)x1[2*p]; h1[1] = (__fp16)x1[2*p+1];
        xp0[p] = h0; xp1[p] = h1;
    }

    // ---- main loop, FULLY unrolled: bperm -> gate(fdot2) -> conv -> SiLU ----
    float m20 = 0.f, m21 = 0.f, ac0 = 0.f, ac1 = 0.f;
    #pragma unroll
    for (int t = 0; t < SS; ++t) {
        // neighbor elems of x_norm row t
        float L2e0 = BPERM(aL2, x0[t]), L2e1 = BPERM(aL2, x1[t]);
        float L1e0 = BPERM(aL1, x0[t]), L1e1 = BPERM(aL1, x1[t]);
        float R1e0 = BPERM(aR1, x0[t]), R1e1 = BPERM(aR1, x1[t]);
        float R2e0 = BPERM(aR2, x0[t]), R2e1 = BPERM(aR2, x1[t]);

        // gate row t: 10 fdot2 per d-element (weights are uniform s_loads)
        float g0 = gate_b[t]; float g1 = g0;
        #pragma unroll
        for (int p = 0; p < SS/2; ++p) {
            const half2_t hw = __builtin_bit_cast(half2_t, gw_pk[t * (SS/2) + p]);
            g0 = gate_dot2(xp0[p], hw, g0);
            g1 = gate_dot2(xp1[p], hw, g1);
        }

        // edge masking ('same' zero padding)
        L1e0 = mL1 ? 0.f : L1e0;  L1e1 = mL1 ? 0.f : L1e1;
        L2e0 = mL2 ? 0.f : L2e0;  L2e1 = mL2 ? 0.f : L2e1;
        R1e0 = mR1 ? 0.f : R1e0;  R1e1 = mR1 ? 0.f : R1e1;
        R2e0 = mR2 ? 0.f : R2e0;  R2e1 = mR2 ? 0.f : R2e1;

        // uniform conv weights (scalar loads, pipelined by full unroll)
        const float wa0 = w0[t*3+0], wa2 = w0[t*3+2];   // dilation 1
        const float wb0 = w1[t*3+0], wb2 = w1[t*3+2];   // dilation 2
        const float wc0 = w2[t*3+0], wc2 = w2[t*3+2];   // dilation 4
        const float cw   = w0[t*3+1] + w1[t*3+1] + w2[t*3+1];
        const float bias = b0[t] + b1[t] + b2[t];

        // conv output j=0 (d = d0)
        float xd0 = bias;
        xd0 = fmaf(wc0, L2e0,  xd0);   // d-4
        xd0 = fmaf(wb0, L1e0,  xd0);   // d-2
        xd0 = fmaf(wa0, L1e1,  xd0);   // d-1
        xd0 = fmaf(cw,  x0[t], xd0);   // d
        xd0 = fmaf(wa2, x1[t], xd0);   // d+1
        xd0 = fmaf(wb2, R1e0,  xd0);   // d+2
        xd0 = fmaf(wc2, R2e0,  xd0);   // d+4
        // conv output j=1 (d = d0+1)
        float xd1 = bias;
        xd1 = fmaf(wc0, L2e1,  xd1);   // d-4
        xd1 = fmaf(wb0, L1e1,  xd1);   // d-2
        xd1 = fmaf(wa0, x0[t], xd1);   // d-1
        xd1 = fmaf(cw,  x1[t], xd1);   // d
        xd1 = fmaf(wa2, R1e0,  xd1);   // d+1
        xd1 = fmaf(wb2, R1e1,  xd1);   // d+2
        xd1 = fmaf(wc2, R2e1,  xd1);   // d+4

        // SiLU + post-RMS accumulation
        const float pl = post_w[t] * logit_w[t];
        const float h0 = xd0 * (g0 * __builtin_amdgcn_rcpf(1.f + __expf(-g0)));
        const float h1 = xd1 * (g1 * __builtin_amdgcn_rcpf(1.f + __expf(-g1)));
        m20 = fmaf(h0, h0, m20);
        m21 = fmaf(h1, h1, m21);
        ac0 = fmaf(h0, pl, ac0);
        ac1 = fmaf(h1, pl, ac1);
    }

    const float q0 = rsqrtf(m20 * (1.f/SS) + EPSV);
    const float q1 = rsqrtf(m21 * (1.f/SS) + EPSV);

    float2 res;
    res.x = a10 + q0 * ac0;
    res.y = a11 + q1 * ac1;
    *reinterpret_cast<float2*>(out + b * DD + d0) = res;
}

extern "C" void kernel_launch(void* const* d_in, const int* in_sizes, int n_in,
                              void* d_out, int out_size, void* d_ws, size_t ws_size,
                              hipStream_t stream) {
    const int*   tokens  = (const int*)  d_in[0];
    // d_in[1] = number_log — unused by the reference
    const float* emb     = (const float*)d_in[2];
    const float* pre_w   = (const float*)d_in[3];
    const float* w0      = (const float*)d_in[4];
    const float* b0      = (const float*)d_in[5];
    const float* w1      = (const float*)d_in[6];
    const float* b1      = (const float*)d_in[7];
    const float* w2      = (const float*)d_in[8];
    const float* b2      = (const float*)d_in[9];
    const float* gate_w  = (const float*)d_in[10];
    const float* gate_b  = (const float*)d_in[11];
    const float* post_w  = (const float*)d_in[12];
    const float* logit_w = (const float*)d_in[13];
    float*       out     = (float*)d_out;
    uint32_t*    ws      = (uint32_t*)d_ws;

    hipLaunchKernelGGL(pack_gate_kernel, dim3(1), dim3(256), 0, stream,
                       gate_w, ws);

    dim3 grid(BB / 4);   // 4 rows (4 waves) per 256-thread block
    dim3 block(256);
    hipLaunchKernelGGL(fused_mdt_kernel, grid, block, 0, stream,
                       tokens, emb, pre_w, w0, b0, w1, b1, w2, b2,
                       (const uint32_t*)ws, gate_b, post_w, logit_w, out);
}

// Round 9
// 57.436 us; speedup vs baseline: 1.1606x; 1.1606x over previous
//
#include <hip/hip_runtime.h>
#include <stdint.h>

// Problem constants (match reference)
#define BB 16384
#define SS 20
#define DD 128
#define EPSV 1e-5f

// R9: one wave = 2 batch rows; 32 lanes/row; each lane owns 4 consecutive d
// (d0 = 4*il) in registers. Conv taps +-1,+-2,+-4 come from the lane's own
// chunk plus neighbor-lane chunks via ds_bpermute: 8 DS ops per t serving 8
// outputs (2 DS/elem, half of R7/R8). Block = 256 (4 waves = 8 rows) fixes
// R5's single-wave-WG residency collapse. Gate via v_dot2_f32_f16 on packed
// f16 (R8-proven). Full unroll (R8: pipelines the weight s_loads). NO
// launch-bounds min-waves arg (R6: forced 64 VGPR -> 230 MB scratch spill).

typedef __fp16 half2_t __attribute__((ext_vector_type(2)));

#define BPERM(addr, v) \
    __int_as_float(__builtin_amdgcn_ds_bpermute((addr), __float_as_int(v)))

#if defined(__has_builtin)
#if __has_builtin(__builtin_amdgcn_fdot2)
#define HAVE_FDOT2 1
#endif
#endif
#ifndef HAVE_FDOT2
#define HAVE_FDOT2 0
#endif

static __device__ __forceinline__ float gate_dot2(half2_t a, half2_t b, float c) {
#if HAVE_FDOT2
    return __builtin_amdgcn_fdot2(a, b, c, false);
#else
    c = fmaf((float)a[0], (float)b[0], c);
    return fmaf((float)a[1], (float)b[1], c);
#endif
}

// ---- prep: pack gate_w [20][20] f32 -> [20][10] f16x2 in ws ----
__global__ void pack_gate_kernel(const float* __restrict__ gate_w,
                                 uint32_t*    __restrict__ ws) {
    const int i = threadIdx.x;            // single block of 256
    if (i < SS * (SS / 2)) {
        const int t = i / (SS / 2), p = i % (SS / 2);
        half2_t h;
        h[0] = (__fp16)gate_w[t * SS + 2 * p];
        h[1] = (__fp16)gate_w[t * SS + 2 * p + 1];
        ws[i] = __builtin_bit_cast(uint32_t, h);
    }
}

__global__ __launch_bounds__(256) void fused_mdt_kernel(
    const int*      __restrict__ tokens,   // [B,S]
    const float*    __restrict__ emb,      // [V,D] (6 KB, cache-resident)
    const float*    __restrict__ pre_w,    // [S]
    const float*    __restrict__ w0, const float* __restrict__ b0,
    const float*    __restrict__ w1, const float* __restrict__ b1,
    const float*    __restrict__ w2, const float* __restrict__ b2,
    const uint32_t* __restrict__ gw_pk,    // [S][S/2] f16x2 (from prep)
    const float*    __restrict__ gate_b,   // [S]
    const float*    __restrict__ post_w,   // [S]
    const float*    __restrict__ logit_w,  // [1,S,1] -> flat [S]
    float*          __restrict__ out)      // [B,1,D] -> flat [B*D]
{
    const int tid  = threadIdx.x;
    const int lane = tid & 63;               // lane within wave
    const int il   = lane & 31;              // lane within row
    const int b    = blockIdx.x * 8 + (tid >> 5);
    const int d0   = il << 2;

    const bool le = (il == 0);               // left row edge (all L taps)
    const bool re = (il == 31);              // right row edge (all R taps)
    const int  la = (lane - 1) << 2;         // bpermute: pull lane-1
    const int  ra = (lane + 1) << 2;         // pull lane+1 (wraps masked)

    // ---- emb gather (tok[] scoped: dies before the main loop) ----
    float x0[SS], x1[SS], x2[SS], x3[SS];
    {
        int tok[SS];
        const int4* t4 = reinterpret_cast<const int4*>(tokens + b * SS);
        #pragma unroll
        for (int i = 0; i < 5; ++i) {
            int4 v = t4[i];
            tok[4*i+0] = v.x; tok[4*i+1] = v.y;
            tok[4*i+2] = v.z; tok[4*i+3] = v.w;
        }
        #pragma unroll
        for (int s = 0; s < SS; ++s) {
            const float4 v = *reinterpret_cast<const float4*>(emb + tok[s] * DD + d0);
            x0[s] = v.x; x1[s] = v.y; x2[s] = v.z; x3[s] = v.w;
        }
    }

    // ---- per-d RMS stats + residual dot ----
    float ms0=0.f, ms1=0.f, ms2=0.f, ms3=0.f;
    float a10=0.f, a11=0.f, a12=0.f, a13=0.f;
    #pragma unroll
    for (int s = 0; s < SS; ++s) {
        ms0 = fmaf(x0[s], x0[s], ms0); ms1 = fmaf(x1[s], x1[s], ms1);
        ms2 = fmaf(x2[s], x2[s], ms2); ms3 = fmaf(x3[s], x3[s], ms3);
        const float lw = logit_w[s];
        a10 = fmaf(x0[s], lw, a10); a11 = fmaf(x1[s], lw, a11);
        a12 = fmaf(x2[s], lw, a12); a13 = fmaf(x3[s], lw, a13);
    }
    const float r0 = rsqrtf(ms0 * (1.f/SS) + EPSV);
    const float r1 = rsqrtf(ms1 * (1.f/SS) + EPSV);
    const float r2 = rsqrtf(ms2 * (1.f/SS) + EPSV);
    const float r3 = rsqrtf(ms3 * (1.f/SS) + EPSV);

    // ---- x_norm in place + f16x2 packed copies for the gate ----
    #pragma unroll
    for (int s = 0; s < SS; ++s) {
        const float pw = pre_w[s];
        x0[s] *= r0 * pw; x1[s] *= r1 * pw;
        x2[s] *= r2 * pw; x3[s] *= r3 * pw;
    }
    half2_t xp0[SS/2], xp1[SS/2], xp2[SS/2], xp3[SS/2];
    #pragma unroll
    for (int p = 0; p < SS/2; ++p) {
        half2_t h;
        h[0] = (__fp16)x0[2*p]; h[1] = (__fp16)x0[2*p+1]; xp0[p] = h;
        h[0] = (__fp16)x1[2*p]; h[1] = (__fp16)x1[2*p+1]; xp1[p] = h;
        h[0] = (__fp16)x2[2*p]; h[1] = (__fp16)x2[2*p+1]; xp2[p] = h;
        h[0] = (__fp16)x3[2*p]; h[1] = (__fp16)x3[2*p+1]; xp3[p] = h;
    }

    // ---- main loop (full unroll): bperm -> gate(fdot2) -> conv -> SiLU ----
    float m20=0.f, m21=0.f, m22=0.f, m23=0.f;
    float ac0=0.f, ac1=0.f, ac2=0.f, ac3=0.f;
    #pragma unroll
    for (int t = 0; t < SS; ++t) {
        // neighbor chunks of x_norm row t (L[k]=d0-4+k, R[k]=d0+4+k)
        float L0 = BPERM(la, x0[t]), L1 = BPERM(la, x1[t]);
        float L2 = BPERM(la, x2[t]), L3 = BPERM(la, x3[t]);
        float R0 = BPERM(ra, x0[t]), R1 = BPERM(ra, x1[t]);
        float R2 = BPERM(ra, x2[t]), R3 = BPERM(ra, x3[t]);

        // gate row t: 10 fdot2 per d-element (uniform packed weights)
        float g0 = gate_b[t]; float g1 = g0, g2 = g0, g3 = g0;
        #pragma unroll
        for (int p = 0; p < SS/2; ++p) {
            const half2_t hw = __builtin_bit_cast(half2_t, gw_pk[t * (SS/2) + p]);
            g0 = gate_dot2(xp0[p], hw, g0);
            g1 = gate_dot2(xp1[p], hw, g1);
            g2 = gate_dot2(xp2[p], hw, g2);
            g3 = gate_dot2(xp3[p], hw, g3);
        }

        // edge masking ('same' zero padding)
        L0 = le ? 0.f : L0; L1 = le ? 0.f : L1;
        L2 = le ? 0.f : L2; L3 = le ? 0.f : L3;
        R0 = re ? 0.f : R0; R1 = re ? 0.f : R1;
        R2 = re ? 0.f : R2; R3 = re ? 0.f : R3;

        // uniform conv weights (scalar loads, pipelined by full unroll)
        const float wa0 = w0[t*3+0], wa2 = w0[t*3+2];   // dilation 1
        const float wb0 = w1[t*3+0], wb2 = w1[t*3+2];   // dilation 2
        const float wc0 = w2[t*3+0], wc2 = w2[t*3+2];   // dilation 4
        const float cw   = w0[t*3+1] + w1[t*3+1] + w2[t*3+1];
        const float bias = b0[t] + b1[t] + b2[t];

        // conv outputs (d = d0+j); tap map verified in R5
        float xd0 = bias;
        xd0 = fmaf(wc0, L0,    xd0);
        xd0 = fmaf(wb0, L2,    xd0);
        xd0 = fmaf(wa0, L3,    xd0);
        xd0 = fmaf(cw,  x0[t], xd0);
        xd0 = fmaf(wa2, x1[t], xd0);
        xd0 = fmaf(wb2, x2[t], xd0);
        xd0 = fmaf(wc2, R0,    xd0);
        float xd1 = bias;
        xd1 = fmaf(wc0, L1,    xd1);
        xd1 = fmaf(wb0, L3,    xd1);
        xd1 = fmaf(wa0, x0[t], xd1);
        xd1 = fmaf(cw,  x1[t], xd1);
        xd1 = fmaf(wa2, x2[t], xd1);
        xd1 = fmaf(wb2, x3[t], xd1);
        xd1 = fmaf(wc2, R1,    xd1);
        float xd2 = bias;
        xd2 = fmaf(wc0, L2,    xd2);
        xd2 = fmaf(wb0, x0[t], xd2);
        xd2 = fmaf(wa0, x1[t], xd2);
        xd2 = fmaf(cw,  x2[t], xd2);
        xd2 = fmaf(wa2, x3[t], xd2);
        xd2 = fmaf(wb2, R0,    xd2);
        xd2 = fmaf(wc2, R2,    xd2);
        float xd3 = bias;
        xd3 = fmaf(wc0, L3,    xd3);
        xd3 = fmaf(wb0, x1[t], xd3);
        xd3 = fmaf(wa0, x2[t], xd3);
        xd3 = fmaf(cw,  x3[t], xd3);
        xd3 = fmaf(wa2, R0,    xd3);
        xd3 = fmaf(wb2, R1,    xd3);
        xd3 = fmaf(wc2, R3,    xd3);

        // SiLU + post-RMS accumulation
        const float pl = post_w[t] * logit_w[t];
        const float h0 = xd0 * (g0 * __builtin_amdgcn_rcpf(1.f + __expf(-g0)));
        const float h1 = xd1 * (g1 * __builtin_amdgcn_rcpf(1.f + __expf(-g1)));
        const float h2 = xd2 * (g2 * __builtin_amdgcn_rcpf(1.f + __expf(-g2)));
        const float h3 = xd3 * (g3 * __builtin_amdgcn_rcpf(1.f + __expf(-g3)));
        m20 = fmaf(h0, h0, m20); m21 = fmaf(h1, h1, m21);
        m22 = fmaf(h2, h2, m22); m23 = fmaf(h3, h3, m23);
        ac0 = fmaf(h0, pl, ac0); ac1 = fmaf(h1, pl, ac1);
        ac2 = fmaf(h2, pl, ac2); ac3 = fmaf(h3, pl, ac3);
    }

    const float q0 = rsqrtf(m20 * (1.f/SS) + EPSV);
    const float q1 = rsqrtf(m21 * (1.f/SS) + EPSV);
    const float q2 = rsqrtf(m22 * (1.f/SS) + EPSV);
    const float q3 = rsqrtf(m23 * (1.f/SS) + EPSV);

    float4 res;
    res.x = a10 + q0 * ac0;
    res.y = a11 + q1 * ac1;
    res.z = a12 + q2 * ac2;
    res.w = a13 + q3 * ac3;
    *reinterpret_cast<float4*>(out + b * DD + d0) = res;
}

extern "C" void kernel_launch(void* const* d_in, const int* in_sizes, int n_in,
                              void* d_out, int out_size, void* d_ws, size_t ws_size,
                              hipStream_t stream) {
    const int*   tokens  = (const int*)  d_in[0];
    // d_in[1] = number_log — unused by the reference
    const float* emb     = (const float*)d_in[2];
    const float* pre_w   = (const float*)d_in[3];
    const float* w0      = (const float*)d_in[4];
    const float* b0      = (const float*)d_in[5];
    const float* w1      = (const float*)d_in[6];
    const float* b1      = (const float*)d_in[7];
    const float* w2      = (const float*)d_in[8];
    const float* b2      = (const float*)d_in[9];
    const float* gate_w  = (const float*)d_in[10];
    const float* gate_b  = (const float*)d_in[11];
    const float* post_w  = (const float*)d_in[12];
    const float* logit_w = (const float*)d_in[13];
    float*       out     = (float*)d_out;
    uint32_t*    ws      = (uint32_t*)d_ws;

    hipLaunchKernelGGL(pack_gate_kernel, dim3(1), dim3(256), 0, stream,
                       gate_w, ws);

    dim3 grid(BB / 8);   // 8 rows per 256-thread block -> 2048 blocks
    dim3 block(256);
    hipLaunchKernelGGL(fused_mdt_kernel, grid, block, 0, stream,
                       tokens, emb, pre_w, w0, b0, w1, b1, w2, b2,
                       (const uint32_t*)ws, gate_b, post_w, logit_w, out);
}